// Round 1
// baseline (6708.656 us; speedup 1.0000x reference)
//
#include <hip/hip_runtime.h>
#include <hip/hip_bf16.h>
#include <cmath>

// Problem constants
constexpr int B  = 8;
constexpr int S  = 1024;
constexpr int P  = 128;
constexpr int D  = 256;
constexpr int H  = 4;
constexpr int L  = 4;
constexpr int DF = 1024;
constexpr int O  = 10;
constexpr int DH = D / H;       // 64
constexpr int SP = S + 1;       // 1025 tokens
constexpr int N  = B * SP;      // 8200 rows

// ---------------------------------------------------------------------------
// Patch embedding + cls + positional embedding
// x[n][d]; n = b*SP + sp. sp==0 -> cls row.
// tokens = images @ Wp^T + bp ; x = concat(cls, tokens) + pos
// ---------------------------------------------------------------------------
__global__ void patch_embed_kernel(const float* __restrict__ images,
                                   const float* __restrict__ Wp,
                                   const float* __restrict__ bp,
                                   const float* __restrict__ cls,
                                   const float* __restrict__ pos,
                                   float* __restrict__ x) {
    int n = blockIdx.x;
    int d = threadIdx.x;           // 0..255
    int b = n / SP, sp = n % SP;
    if (sp == 0) {
        x[(size_t)n * D + d] = cls[d] + pos[d];
        return;                    // uniform across block: safe
    }
    int s = sp - 1;
    __shared__ float img[P];
    if (d < P) img[d] = images[((size_t)b * S + s) * P + d];
    __syncthreads();
    float acc = bp[d];
    const float* wrow = Wp + (size_t)d * P;
#pragma unroll 8
    for (int p = 0; p < P; ++p) acc += img[p] * wrow[p];
    x[(size_t)n * D + d] = acc + pos[(size_t)sp * D + d];
}

// ---------------------------------------------------------------------------
// LayerNorm over D=256, one block (256 threads = 4 waves) per row
// ---------------------------------------------------------------------------
__global__ void layernorm_kernel(const float* __restrict__ src,
                                 const float* __restrict__ g,
                                 const float* __restrict__ bb,
                                 float* __restrict__ dst) {
    int n = blockIdx.x, t = threadIdx.x;
    float v = src[(size_t)n * D + t];
    __shared__ float red[4];

    float s = v;
    for (int off = 32; off; off >>= 1) s += __shfl_xor(s, off, 64);
    if ((t & 63) == 0) red[t >> 6] = s;
    __syncthreads();
    float mean = (red[0] + red[1] + red[2] + red[3]) * (1.0f / D);

    float d0 = v - mean;
    float sq = d0 * d0;
    for (int off = 32; off; off >>= 1) sq += __shfl_xor(sq, off, 64);
    __syncthreads();               // protect red[] reuse
    if ((t & 63) == 0) red[t >> 6] = sq;
    __syncthreads();
    float var = (red[0] + red[1] + red[2] + red[3]) * (1.0f / D);

    dst[(size_t)n * D + t] = d0 * rsqrtf(var + 1e-5f) * g[t] + bb[t];
}

// ---------------------------------------------------------------------------
// QKV projection per head: q[b,h,sp,e] = sum_d ln[n, h*64+d] * Wq[h,e,d] + bq[h,e]
// Weights passed pre-offset to layer l. One block per token, 256 threads.
// Outputs laid out [B][H][SP][DH] for attention.
// ---------------------------------------------------------------------------
__global__ void qkv_kernel(const float* __restrict__ ln,
                           const float* __restrict__ Wq, const float* __restrict__ bq,
                           const float* __restrict__ Wk, const float* __restrict__ bk,
                           const float* __restrict__ Wv, const float* __restrict__ bv,
                           float* __restrict__ q, float* __restrict__ k,
                           float* __restrict__ v) {
    int n = blockIdx.x;
    int t = threadIdx.x;           // 0..255
    int h = t >> 6, e = t & 63;
    int b = n / SP, sp = n % SP;

    __shared__ float xr[D];
    xr[t] = ln[(size_t)n * D + t];
    __syncthreads();

    const float* xh = &xr[h * DH];
    int wbase = (h * DH + e) * DH;
    float aq = bq[h * DH + e];
    float ak = bk[h * DH + e];
    float av = bv[h * DH + e];
#pragma unroll 8
    for (int d = 0; d < DH; ++d) {
        float xv = xh[d];
        aq += xv * Wq[wbase + d];
        ak += xv * Wk[wbase + d];
        av += xv * Wv[wbase + d];
    }
    size_t oi = (((size_t)b * H + h) * SP + sp) * DH + e;
    q[oi] = aq; k[oi] = ak; v[oi] = av;
}

// ---------------------------------------------------------------------------
// Attention: one wave (64 threads) per (b,h,query-row).
// scores row (1025 floats) lives in LDS; softmax; PV; residual-add into x.
// ---------------------------------------------------------------------------
__global__ void attn_kernel(const float* __restrict__ q,
                            const float* __restrict__ k,
                            const float* __restrict__ v,
                            float* __restrict__ x) {
    int blk = blockIdx.x;              // (b*H + h)*SP + sp
    int sp  = blk % SP;
    int bh  = blk / SP;
    int h   = bh % H, b = bh / H;
    int t   = threadIdx.x;             // 0..63

    __shared__ float qs[DH];
    __shared__ float sc[SP];

    const float* kbase = k + (size_t)bh * SP * DH;
    const float* vbase = v + (size_t)bh * SP * DH;
    qs[t] = q[((size_t)bh * SP + sp) * DH + t];
    __syncthreads();

    float lmax = -1e30f;
    for (int j = t; j < SP; j += 64) {
        const float* kr = kbase + (size_t)j * DH;
        float s = 0.f;
#pragma unroll 16
        for (int d = 0; d < DH; ++d) s += qs[d] * kr[d];
        s *= 0.125f;                   // 1/sqrt(64)
        sc[j] = s;
        lmax = fmaxf(lmax, s);
    }
    for (int off = 32; off; off >>= 1) lmax = fmaxf(lmax, __shfl_xor(lmax, off, 64));
    __syncthreads();

    float lsum = 0.f;
    for (int j = t; j < SP; j += 64) {
        float e = expf(sc[j] - lmax);
        sc[j] = e;
        lsum += e;
    }
    for (int off = 32; off; off >>= 1) lsum += __shfl_xor(lsum, off, 64);
    __syncthreads();

    float inv = 1.0f / lsum;
    float acc = 0.f;
    for (int j = 0; j < SP; ++j) acc += sc[j] * vbase[(size_t)j * DH + t];

    x[((size_t)b * SP + sp) * D + h * DH + t] += acc * inv;
}

// ---------------------------------------------------------------------------
// Tiled f32 GEMM: Y = epi(X @ W^T + bias).  X: Nrows x K, W: F x K (row-major).
// 64x64 tile, 256 threads, 4x4 register blocking, K-step 16.
// EPI: 0 = store, 1 = exact-GELU store, 2 = residual add into Y.
// ---------------------------------------------------------------------------
template <int EPI>
__global__ void gemm_xwt(const float* __restrict__ X, const float* __restrict__ W,
                         const float* __restrict__ bias, float* __restrict__ Y,
                         int Nrows, int F, int K) {
    __shared__ float As[16][65];
    __shared__ float Bs[16][65];
    const int t  = threadIdx.y * 16 + threadIdx.x;
    const int lk = t & 15;        // k index for loads
    const int lr = t >> 4;        // row-group for loads
    const int tx = threadIdx.x, ty = threadIdx.y;
    const int n0 = blockIdx.y * 64, f0 = blockIdx.x * 64;

    float acc[4][4] = {};
    for (int k0 = 0; k0 < K; k0 += 16) {
#pragma unroll
        for (int i = 0; i < 4; ++i) {
            int nn  = lr + 16 * i;
            int row = n0 + nn;
            As[lk][nn] = (row < Nrows) ? X[(size_t)row * K + k0 + lk] : 0.f;
            Bs[lk][nn] = W[(size_t)(f0 + nn) * K + k0 + lk];
        }
        __syncthreads();
#pragma unroll
        for (int kk = 0; kk < 16; ++kk) {
            float a[4], bvals[4];
#pragma unroll
            for (int i = 0; i < 4; ++i) a[i] = As[kk][ty + 16 * i];
#pragma unroll
            for (int j = 0; j < 4; ++j) bvals[j] = Bs[kk][tx + 16 * j];
#pragma unroll
            for (int i = 0; i < 4; ++i)
#pragma unroll
                for (int j = 0; j < 4; ++j) acc[i][j] += a[i] * bvals[j];
        }
        __syncthreads();
    }

#pragma unroll
    for (int i = 0; i < 4; ++i) {
        int n = n0 + ty + 16 * i;
        if (n >= Nrows) continue;
#pragma unroll
        for (int j = 0; j < 4; ++j) {
            int f = f0 + tx + 16 * j;
            float val = acc[i][j] + bias[f];
            if (EPI == 1) val = 0.5f * val * (1.0f + erff(val * 0.70710678118654752f));
            size_t idx = (size_t)n * F + f;
            if (EPI == 2) Y[idx] += val;
            else          Y[idx] = val;
        }
    }
}

// ---------------------------------------------------------------------------
// Final head: logits = x[:,0] @ Wo^T + bo ; softmax. One block.
// ---------------------------------------------------------------------------
__global__ void head_kernel(const float* __restrict__ x,
                            const float* __restrict__ Wo,
                            const float* __restrict__ bo,
                            float* __restrict__ out) {
    __shared__ float logits[B][O];
    int t = threadIdx.x;
    if (t < B * O) {
        int b = t / O, o = t % O;
        const float* xr = x + (size_t)b * SP * D;    // token 0 of batch b
        float acc = bo[o];
        for (int d = 0; d < D; ++d) acc += xr[d] * Wo[(size_t)o * D + d];
        logits[b][o] = acc;
    }
    __syncthreads();
    if (t < B) {
        float mx = -1e30f;
        for (int o = 0; o < O; ++o) mx = fmaxf(mx, logits[t][o]);
        float s = 0.f, e[O];
        for (int o = 0; o < O; ++o) { e[o] = expf(logits[t][o] - mx); s += e[o]; }
        float inv = 1.0f / s;
        for (int o = 0; o < O; ++o) out[t * O + o] = e[o] * inv;
    }
}

// ---------------------------------------------------------------------------
extern "C" void kernel_launch(void* const* d_in, const int* in_sizes, int n_in,
                              void* d_out, int out_size, void* d_ws, size_t ws_size,
                              hipStream_t stream) {
    const float* images = (const float*)d_in[0];
    const float* Wp     = (const float*)d_in[1];
    const float* bp     = (const float*)d_in[2];
    const float* cls    = (const float*)d_in[3];
    const float* pos    = (const float*)d_in[4];
    const float* ln1_g  = (const float*)d_in[5];
    const float* ln1_b  = (const float*)d_in[6];
    const float* Wq     = (const float*)d_in[7];
    const float* bq     = (const float*)d_in[8];
    const float* Wk     = (const float*)d_in[9];
    const float* bk     = (const float*)d_in[10];
    const float* Wv     = (const float*)d_in[11];
    const float* bv     = (const float*)d_in[12];
    const float* ln2_g  = (const float*)d_in[13];
    const float* ln2_b  = (const float*)d_in[14];
    const float* W1     = (const float*)d_in[15];
    const float* b1     = (const float*)d_in[16];
    const float* W2     = (const float*)d_in[17];
    const float* b2     = (const float*)d_in[18];
    const float* Wo     = (const float*)d_in[19];
    const float* bo     = (const float*)d_in[20];
    float* out = (float*)d_out;

    float* ws  = (float*)d_ws;
    float* x   = ws;                           // N*D
    float* ln  = x  + (size_t)N * D;           // N*D
    float* qb  = ln + (size_t)N * D;           // N*D
    float* kb  = qb + (size_t)N * D;           // N*D
    float* vb  = kb + (size_t)N * D;           // N*D
    float* mid = vb + (size_t)N * D;           // N*DF

    patch_embed_kernel<<<N, D, 0, stream>>>(images, Wp, bp, cls, pos, x);

    for (int l = 0; l < L; ++l) {
        layernorm_kernel<<<N, 256, 0, stream>>>(x, ln1_g + l * D, ln1_b + l * D, ln);
        qkv_kernel<<<N, 256, 0, stream>>>(ln,
                                          Wq + (size_t)l * H * DH * DH, bq + (size_t)l * H * DH,
                                          Wk + (size_t)l * H * DH * DH, bk + (size_t)l * H * DH,
                                          Wv + (size_t)l * H * DH * DH, bv + (size_t)l * H * DH,
                                          qb, kb, vb);
        attn_kernel<<<B * H * SP, 64, 0, stream>>>(qb, kb, vb, x);
        layernorm_kernel<<<N, 256, 0, stream>>>(x, ln2_g + l * D, ln2_b + l * D, ln);
        gemm_xwt<1><<<dim3(DF / 64, (N + 63) / 64), dim3(16, 16), 0, stream>>>(
            ln, W1 + (size_t)l * DF * D, b1 + (size_t)l * DF, mid, N, DF, D);
        gemm_xwt<2><<<dim3(D / 64, (N + 63) / 64), dim3(16, 16), 0, stream>>>(
            mid, W2 + (size_t)l * D * DF, b2 + (size_t)l * D, x, N, D, DF);
    }

    head_kernel<<<1, 256, 0, stream>>>(x, Wo, bo, out);
}

// Round 2
// 699.585 us; speedup vs baseline: 9.5895x; 9.5895x over previous
//
#include <hip/hip_runtime.h>
#include <hip/hip_bf16.h>
#include <cmath>

constexpr int B  = 8;
constexpr int S  = 1024;
constexpr int P  = 128;
constexpr int D  = 256;
constexpr int H  = 4;
constexpr int L  = 4;
constexpr int DF = 1024;
constexpr int O  = 10;
constexpr int DH = D / H;       // 64
constexpr int SP = S + 1;       // 1025
constexpr int N  = B * SP;      // 8200

typedef short bf16x8 __attribute__((ext_vector_type(8)));
typedef float f32x4 __attribute__((ext_vector_type(4)));
typedef unsigned int u32;
typedef unsigned short u16;

static __device__ __forceinline__ u16 f2b(float f) {
    __hip_bfloat16 h = __float2bfloat16(f);
    u16 u; __builtin_memcpy(&u, &h, 2);
    return u;
}
static __device__ __forceinline__ u32 pk2(float a, float b) {
    return (u32)f2b(a) | ((u32)f2b(b) << 16);
}

// ---------------------------------------------------------------------------
// f32 -> bf16 bulk convert (n4 = n/4 float4 groups)
// ---------------------------------------------------------------------------
__global__ void cvt_bf16(const float* __restrict__ src, u16* __restrict__ dst, int n4) {
    int i = blockIdx.x * 256 + threadIdx.x;
    if (i < n4) {
        float4 v = ((const float4*)src)[i];
        ushort4 o;
        o.x = f2b(v.x); o.y = f2b(v.y); o.z = f2b(v.z); o.w = f2b(v.w);
        ((ushort4*)dst)[i] = o;
    }
}

// ---------------------------------------------------------------------------
// cls rows: x[b*SP*D + d] = cls[d] + pos[d]
// ---------------------------------------------------------------------------
__global__ void cls_kernel(const float* __restrict__ cls, const float* __restrict__ pos,
                           float* __restrict__ x) {
    int b = blockIdx.x, t = threadIdx.x;
    x[(size_t)b * SP * D + t] = cls[t] + pos[t];
}

// ---------------------------------------------------------------------------
// MFMA GEMM: Y = epi(X @ W^T + bias). X[M][K] bf16, W[F][K] bf16.
// BM=64 BN=128 BK=32, 256 threads = 4 waves (2x2), each wave 32x64 (2x4 frags).
// EPI 0: patch-embed epilogue (row remap + pos add, f32 out)
// EPI 1: exact GELU -> bf16 out
// EPI 2: f32 residual add (Yf += val)
// ---------------------------------------------------------------------------
template <int EPI>
__global__ void gemm_bf16(const u16* __restrict__ X, const u16* __restrict__ W,
                          const float* __restrict__ bias, const float* __restrict__ pos,
                          float* __restrict__ Yf, u16* __restrict__ Yb,
                          int M, int F, int K) {
    __shared__ u16 Al[64][40];
    __shared__ u16 Bl[128][40];
    const int t = threadIdx.x;
    const int m0 = blockIdx.y * 64, f0 = blockIdx.x * 128;
    const int w = t >> 6, l = t & 63;
    const int wm = w >> 1, wn = w & 1;
    const int q = l & 15, g = l >> 4;

    f32x4 acc[2][4];
    const f32x4 zz = {0.f, 0.f, 0.f, 0.f};
#pragma unroll
    for (int i = 0; i < 2; ++i)
#pragma unroll
        for (int j = 0; j < 4; ++j) acc[i][j] = zz;

    const int lrow = t >> 2, lc8 = (t & 3) * 8;
    for (int k0 = 0; k0 < K; k0 += 32) {
        uint4 av = {0, 0, 0, 0};
        if (m0 + lrow < M) av = *(const uint4*)(X + (size_t)(m0 + lrow) * K + k0 + lc8);
        *(uint4*)&Al[lrow][lc8] = av;
#pragma unroll
        for (int it = 0; it < 2; ++it) {
            int row = lrow + 64 * it;
            *(uint4*)&Bl[row][lc8] = *(const uint4*)(W + (size_t)(f0 + row) * K + k0 + lc8);
        }
        __syncthreads();
        bf16x8 a[2], bfr[4];
#pragma unroll
        for (int fi = 0; fi < 2; ++fi) a[fi] = *(const bf16x8*)&Al[wm * 32 + fi * 16 + q][g * 8];
#pragma unroll
        for (int fj = 0; fj < 4; ++fj) bfr[fj] = *(const bf16x8*)&Bl[wn * 64 + fj * 16 + q][g * 8];
#pragma unroll
        for (int fi = 0; fi < 2; ++fi)
#pragma unroll
            for (int fj = 0; fj < 4; ++fj)
                acc[fi][fj] = __builtin_amdgcn_mfma_f32_16x16x32_bf16(a[fi], bfr[fj], acc[fi][fj], 0, 0, 0);
        __syncthreads();
    }

#pragma unroll
    for (int fi = 0; fi < 2; ++fi) {
#pragma unroll
        for (int r = 0; r < 4; ++r) {
            int m = m0 + wm * 32 + fi * 16 + g * 4 + r;
            if (m >= M) continue;
#pragma unroll
            for (int fj = 0; fj < 4; ++fj) {
                int f = f0 + wn * 64 + fj * 16 + q;
                float val = acc[fi][fj][r] + bias[f];
                if constexpr (EPI == 0) {
                    int s = m & 1023, bb = m >> 10;
                    size_t n = (size_t)bb * SP + s + 1;
                    Yf[n * D + f] = val + pos[(size_t)(s + 1) * D + f];
                } else if constexpr (EPI == 1) {
                    float gel = 0.5f * val * (1.0f + erff(val * 0.70710678118654752f));
                    Yb[(size_t)m * F + f] = f2b(gel);
                } else {
                    Yf[(size_t)m * F + f] += val;
                }
            }
        }
    }
}

// ---------------------------------------------------------------------------
// LayerNorm over D=256, one block per row. OUTB: 0 -> f32 dst, 1 -> bf16 dst
// ---------------------------------------------------------------------------
template <int OUTB>
__global__ void layernorm_kernel(const float* __restrict__ src,
                                 const float* __restrict__ gg,
                                 const float* __restrict__ bb,
                                 float* __restrict__ dstf, u16* __restrict__ dstb) {
    int n = blockIdx.x, t = threadIdx.x;
    float v = src[(size_t)n * D + t];
    __shared__ float red[4];

    float s = v;
    for (int off = 32; off; off >>= 1) s += __shfl_xor(s, off, 64);
    if ((t & 63) == 0) red[t >> 6] = s;
    __syncthreads();
    float mean = (red[0] + red[1] + red[2] + red[3]) * (1.0f / D);

    float d0 = v - mean;
    float sq = d0 * d0;
    for (int off = 32; off; off >>= 1) sq += __shfl_xor(sq, off, 64);
    __syncthreads();
    if ((t & 63) == 0) red[t >> 6] = sq;
    __syncthreads();
    float var = (red[0] + red[1] + red[2] + red[3]) * (1.0f / D);

    float out = d0 * rsqrtf(var + 1e-5f) * gg[t] + bb[t];
    if constexpr (OUTB == 0) dstf[(size_t)n * D + t] = out;
    else                     dstb[(size_t)n * D + t] = f2b(out);
}

// ---------------------------------------------------------------------------
// QKV: 4 tokens/block, one head/block (grid 2050 x 4). W staged in padded LDS.
// Outputs bf16 [B][H][SP][DH]; q pre-scaled by 1/8.
// ---------------------------------------------------------------------------
__global__ void qkv_kernel(const float* __restrict__ ln,
                           const float* __restrict__ Wq, const float* __restrict__ bq,
                           const float* __restrict__ Wk, const float* __restrict__ bk,
                           const float* __restrict__ Wv, const float* __restrict__ bv,
                           u16* __restrict__ qo, u16* __restrict__ ko, u16* __restrict__ vo) {
    const int h = blockIdx.y;
    const int n0 = blockIdx.x * 4;
    const int t = threadIdx.x;
    const int tt = t >> 6, e = t & 63;

    __shared__ float Wql[64][65], Wkl[64][65], Wvl[64][65];
    __shared__ float xs[4][64];

    const float* wqh = Wq + (size_t)h * 64 * 64;
    const float* wkh = Wk + (size_t)h * 64 * 64;
    const float* wvh = Wv + (size_t)h * 64 * 64;
    for (int i = t; i < 4096; i += 256) {
        int er = i >> 6, d = i & 63;
        Wql[er][d] = wqh[i];
        Wkl[er][d] = wkh[i];
        Wvl[er][d] = wvh[i];
    }
    xs[tt][e] = ln[(size_t)(n0 + tt) * D + h * 64 + e];
    __syncthreads();

    float aq = bq[h * 64 + e], ak = bk[h * 64 + e], av = bv[h * 64 + e];
#pragma unroll 8
    for (int d = 0; d < 64; ++d) {
        float xv = xs[tt][d];
        aq += xv * Wql[e][d];
        ak += xv * Wkl[e][d];
        av += xv * Wvl[e][d];
    }
    int n = n0 + tt;
    int bI = n / SP, sp = n % SP;
    size_t oi = (((size_t)bI * H + h) * SP + sp) * DH + e;
    qo[oi] = f2b(aq * 0.125f);
    ko[oi] = f2b(ak);
    vo[oi] = f2b(av);
}

// ---------------------------------------------------------------------------
// Flash attention, MFMA. grid (17 q-tiles, 32 bh). 256 thr = 4 waves,
// 16 q-rows per wave. KV tiles of 32 staged in LDS. Residual-adds into x.
// ---------------------------------------------------------------------------
__global__ void attn_mfma(const u16* __restrict__ qb, const u16* __restrict__ kb,
                          const u16* __restrict__ vb, float* __restrict__ x) {
    const int qt = blockIdx.x, bh = blockIdx.y;
    const int h = bh & 3, b = bh >> 2;
    const int t = threadIdx.x, w = t >> 6, l = t & 63;
    const int q = l & 15, g = l >> 4;
    const int q0 = qt * 64 + w * 16;

    __shared__ u16 Kl[32][72];   // rows padded 64->72 (144B, 16B-aligned)
    __shared__ u16 Vt[64][40];   // transposed V, cols padded 32->40

    const u16* Kb = kb + (size_t)bh * SP * DH;
    const u16* Vb = vb + (size_t)bh * SP * DH;
    const u16* Qb = qb + (size_t)bh * SP * DH;

    bf16x8 qf[2];
    {
        int qr = q0 + q; if (qr > S) qr = S;
        const u16* qp = Qb + (size_t)qr * DH;
        qf[0] = *(const bf16x8*)(qp + g * 8);
        qf[1] = *(const bf16x8*)(qp + 32 + g * 8);
    }

    f32x4 o[4];
    const f32x4 zz = {0.f, 0.f, 0.f, 0.f};
#pragma unroll
    for (int d = 0; d < 4; ++d) o[d] = zz;
    float m_run = -1e30f, l_run = 0.f;

    const int skv = t >> 3, sc8 = (t & 7) * 8;

    for (int kv0 = 0; kv0 < SP; kv0 += 32) {
        {   // stage K row-major, V transposed
            int kvr = kv0 + skv; if (kvr > S) kvr = S;
            uint4 kvv = *(const uint4*)(Kb + (size_t)kvr * DH + sc8);
            *(uint4*)&Kl[skv][sc8] = kvv;
            uint4 vvv = *(const uint4*)(Vb + (size_t)kvr * DH + sc8);
            const u16* pv = (const u16*)&vvv;
#pragma unroll
            for (int j = 0; j < 8; ++j) Vt[sc8 + j][skv] = pv[j];
        }
        __syncthreads();

        // swapped QK^T: S^T[kv][q]
        f32x4 s1 = zz, s2 = zz;
        {
            bf16x8 k00 = *(const bf16x8*)&Kl[q][g * 8];
            bf16x8 k01 = *(const bf16x8*)&Kl[q][32 + g * 8];
            bf16x8 k10 = *(const bf16x8*)&Kl[16 + q][g * 8];
            bf16x8 k11 = *(const bf16x8*)&Kl[16 + q][32 + g * 8];
            s1 = __builtin_amdgcn_mfma_f32_16x16x32_bf16(k00, qf[0], s1, 0, 0, 0);
            s1 = __builtin_amdgcn_mfma_f32_16x16x32_bf16(k01, qf[1], s1, 0, 0, 0);
            s2 = __builtin_amdgcn_mfma_f32_16x16x32_bf16(k10, qf[0], s2, 0, 0, 0);
            s2 = __builtin_amdgcn_mfma_f32_16x16x32_bf16(k11, qf[1], s2, 0, 0, 0);
        }

        float sv[8];
#pragma unroll
        for (int r = 0; r < 4; ++r) { sv[r] = s1[r]; sv[4 + r] = s2[r]; }
        if (kv0 + 32 > SP) {
#pragma unroll
            for (int r = 0; r < 4; ++r) {
                if (kv0 + g * 4 + r >= SP)      sv[r]     = -1e30f;
                if (kv0 + 16 + g * 4 + r >= SP) sv[4 + r] = -1e30f;
            }
        }
        float mt = sv[0];
#pragma unroll
        for (int j = 1; j < 8; ++j) mt = fmaxf(mt, sv[j]);
        mt = fmaxf(mt, __shfl_xor(mt, 16));
        mt = fmaxf(mt, __shfl_xor(mt, 32));
        float m_new = fmaxf(m_run, mt);
        float corr = __expf(m_run - m_new);
        float ps = 0.f;
#pragma unroll
        for (int j = 0; j < 8; ++j) { sv[j] = __expf(sv[j] - m_new); ps += sv[j]; }
        ps += __shfl_xor(ps, 16);
        ps += __shfl_xor(ps, 32);
        l_run = l_run * corr + ps;
        m_run = m_new;

        // rescale O rows (row = g*4+r in O layout)
#pragma unroll
        for (int r = 0; r < 4; ++r) {
            float sc = __shfl(corr, g * 4 + r);
#pragma unroll
            for (int d = 0; d < 4; ++d) o[d][r] *= sc;
        }

        // pack P -> bf16 and redistribute to A-fragment layout
        u32 t1a = pk2(sv[0], sv[1]), t1b = pk2(sv[2], sv[3]);
        u32 t2a = pk2(sv[4], sv[5]), t2b = pk2(sv[6], sv[7]);
        int s0i = q + 16 * ((2 * g) & 3);
        int s1i = q + 16 * ((2 * g + 1) & 3);
        u32 c0a = (u32)__shfl((int)t1a, s0i), c0b = (u32)__shfl((int)t1b, s0i);
        u32 d0a = (u32)__shfl((int)t2a, s0i), d0b = (u32)__shfl((int)t2b, s0i);
        u32 c1a = (u32)__shfl((int)t1a, s1i), c1b = (u32)__shfl((int)t1b, s1i);
        u32 d1a = (u32)__shfl((int)t2a, s1i), d1b = (u32)__shfl((int)t2b, s1i);
        union { u32 u[4]; bf16x8 v; } pa;
        pa.u[0] = (g < 2) ? c0a : d0a;
        pa.u[1] = (g < 2) ? c0b : d0b;
        pa.u[2] = (g < 2) ? c1a : d1a;
        pa.u[3] = (g < 2) ? c1b : d1b;

#pragma unroll
        for (int d = 0; d < 4; ++d) {
            bf16x8 vf = *(const bf16x8*)&Vt[d * 16 + q][g * 8];
            o[d] = __builtin_amdgcn_mfma_f32_16x16x32_bf16(pa.v, vf, o[d], 0, 0, 0);
        }
        __syncthreads();
    }

    float inv = 1.0f / l_run;
#pragma unroll
    for (int r = 0; r < 4; ++r) {
        float sc = __shfl(inv, g * 4 + r);
        int qrow = q0 + g * 4 + r;
        if (qrow < SP) {
            float* xp = &x[((size_t)b * SP + qrow) * D + h * DH];
#pragma unroll
            for (int d = 0; d < 4; ++d) xp[d * 16 + q] += o[d][r] * sc;
        }
    }
}

// ---------------------------------------------------------------------------
// Final head
// ---------------------------------------------------------------------------
__global__ void head_kernel(const float* __restrict__ x,
                            const float* __restrict__ Wo,
                            const float* __restrict__ bo,
                            float* __restrict__ out) {
    __shared__ float logits[B][O];
    int t = threadIdx.x;
    if (t < B * O) {
        int b = t / O, o = t % O;
        const float* xr = x + (size_t)b * SP * D;
        float acc = bo[o];
        for (int d = 0; d < D; ++d) acc += xr[d] * Wo[(size_t)o * D + d];
        logits[b][o] = acc;
    }
    __syncthreads();
    if (t < B) {
        float mx = -1e30f;
        for (int o = 0; o < O; ++o) mx = fmaxf(mx, logits[t][o]);
        float s = 0.f, e[O];
        for (int o = 0; o < O; ++o) { e[o] = expf(logits[t][o] - mx); s += e[o]; }
        float inv = 1.0f / s;
        for (int o = 0; o < O; ++o) out[t * O + o] = e[o] * inv;
    }
}

// ---------------------------------------------------------------------------
extern "C" void kernel_launch(void* const* d_in, const int* in_sizes, int n_in,
                              void* d_out, int out_size, void* d_ws, size_t ws_size,
                              hipStream_t stream) {
    const float* images = (const float*)d_in[0];
    const float* Wp     = (const float*)d_in[1];
    const float* bp     = (const float*)d_in[2];
    const float* cls    = (const float*)d_in[3];
    const float* pos    = (const float*)d_in[4];
    const float* ln1_g  = (const float*)d_in[5];
    const float* ln1_b  = (const float*)d_in[6];
    const float* Wq     = (const float*)d_in[7];
    const float* bq     = (const float*)d_in[8];
    const float* Wk     = (const float*)d_in[9];
    const float* bk     = (const float*)d_in[10];
    const float* Wv     = (const float*)d_in[11];
    const float* bv     = (const float*)d_in[12];
    const float* ln2_g  = (const float*)d_in[13];
    const float* ln2_b  = (const float*)d_in[14];
    const float* W1     = (const float*)d_in[15];
    const float* b1     = (const float*)d_in[16];
    const float* W2     = (const float*)d_in[17];
    const float* b2     = (const float*)d_in[18];
    const float* Wo     = (const float*)d_in[19];
    const float* bo     = (const float*)d_in[20];
    float* out = (float*)d_out;

    char* p = (char*)d_ws;
    float* x    = (float*)p; p += (size_t)N * D * 4;
    float* lnf  = (float*)p; p += (size_t)N * D * 4;
    u16* lnb    = (u16*)p;   p += (size_t)N * D * 2;
    u16* qbuf   = (u16*)p;   p += (size_t)N * D * 2;
    u16* kbuf   = (u16*)p;   p += (size_t)N * D * 2;
    u16* vbuf   = (u16*)p;   p += (size_t)N * D * 2;
    u16* mid    = (u16*)p;   p += (size_t)N * DF * 2;
    u16* imgb   = (u16*)p;   p += (size_t)B * S * P * 2;
    u16* Wpb    = (u16*)p;   p += (size_t)D * P * 2;
    u16* W1b    = (u16*)p;   p += (size_t)L * DF * D * 2;
    u16* W2b    = (u16*)p;   p += (size_t)L * D * DF * 2;

    // weight / input conversions
    cvt_bf16<<<(B * S * P / 4 + 255) / 256, 256, 0, stream>>>(images, imgb, B * S * P / 4);
    cvt_bf16<<<(D * P / 4 + 255) / 256, 256, 0, stream>>>(Wp, Wpb, D * P / 4);
    cvt_bf16<<<(L * DF * D / 4 + 255) / 256, 256, 0, stream>>>(W1, W1b, L * DF * D / 4);
    cvt_bf16<<<(L * D * DF / 4 + 255) / 256, 256, 0, stream>>>(W2, W2b, L * D * DF / 4);

    // patch embed as GEMM (M=8192, F=256, K=128) + cls rows
    gemm_bf16<0><<<dim3(D / 128, (B * S) / 64), 256, 0, stream>>>(
        imgb, Wpb, bp, pos, x, nullptr, B * S, D, P);
    cls_kernel<<<B, D, 0, stream>>>(cls, pos, x);

    for (int l = 0; l < L; ++l) {
        layernorm_kernel<0><<<N, D, 0, stream>>>(x, ln1_g + l * D, ln1_b + l * D, lnf, nullptr);
        qkv_kernel<<<dim3(N / 4, H), 256, 0, stream>>>(
            lnf,
            Wq + (size_t)l * H * DH * DH, bq + (size_t)l * H * DH,
            Wk + (size_t)l * H * DH * DH, bk + (size_t)l * H * DH,
            Wv + (size_t)l * H * DH * DH, bv + (size_t)l * H * DH,
            qbuf, kbuf, vbuf);
        attn_mfma<<<dim3(17, B * H), 256, 0, stream>>>(qbuf, kbuf, vbuf, x);
        layernorm_kernel<1><<<N, D, 0, stream>>>(x, ln2_g + l * D, ln2_b + l * D, nullptr, lnb);
        gemm_bf16<1><<<dim3(DF / 128, (N + 63) / 64), 256, 0, stream>>>(
            lnb, W1b + (size_t)l * DF * D, b1 + (size_t)l * DF, nullptr, nullptr, mid, N, DF, D);
        gemm_bf16<2><<<dim3(D / 128, (N + 63) / 64), 256, 0, stream>>>(
            mid, W2b + (size_t)l * D * DF, b2 + (size_t)l * D, nullptr, x, nullptr, N, D, DF);
    }

    head_kernel<<<1, 256, 0, stream>>>(x, Wo, bo, out);
}

// Round 3
// 472.581 us; speedup vs baseline: 14.1958x; 1.4803x over previous
//
#include <hip/hip_runtime.h>
#include <hip/hip_bf16.h>
#include <cmath>

constexpr int B  = 8;
constexpr int S  = 1024;
constexpr int P  = 128;
constexpr int D  = 256;
constexpr int H  = 4;
constexpr int L  = 4;
constexpr int DF = 1024;
constexpr int O  = 10;
constexpr int DH = D / H;       // 64
constexpr int SP = S + 1;       // 1025
constexpr int N  = B * SP;      // 8200

typedef short bf16x8 __attribute__((ext_vector_type(8)));
typedef float f32x4 __attribute__((ext_vector_type(4)));
typedef unsigned int u32;
typedef unsigned short u16;

static __device__ __forceinline__ u16 f2b(float f) {
    __hip_bfloat16 h = __float2bfloat16(f);
    u16 u; __builtin_memcpy(&u, &h, 2);
    return u;
}
static __device__ __forceinline__ u32 pk2(float a, float b) {
    return (u32)f2b(a) | ((u32)f2b(b) << 16);
}

// ---------------------------------------------------------------------------
__global__ void cvt_bf16(const float* __restrict__ src, u16* __restrict__ dst, int n4) {
    int i = blockIdx.x * 256 + threadIdx.x;
    if (i < n4) {
        float4 v = ((const float4*)src)[i];
        ushort4 o;
        o.x = f2b(v.x); o.y = f2b(v.y); o.z = f2b(v.z); o.w = f2b(v.w);
        ((ushort4*)dst)[i] = o;
    }
}

// ---------------------------------------------------------------------------
__global__ void cls_kernel(const float* __restrict__ cls, const float* __restrict__ pos,
                           float* __restrict__ x) {
    int b = blockIdx.x, t = threadIdx.x;
    x[(size_t)b * SP * D + t] = cls[t] + pos[t];
}

// ---------------------------------------------------------------------------
// Fused block-diagonal QKV weight builder: Wout[l][768][256] bf16, bout[l][768].
// rows 0..255 = Q (scaled 1/8), 256..511 = K, 512..767 = V.
// ---------------------------------------------------------------------------
__global__ void build_wqkv(const float* __restrict__ Wq, const float* __restrict__ bq,
                           const float* __restrict__ Wk, const float* __restrict__ bk,
                           const float* __restrict__ Wv, const float* __restrict__ bv,
                           u16* __restrict__ Wout, float* __restrict__ bout) {
    int r = blockIdx.x, l = blockIdx.y, c = threadIdx.x;
    int sec = r >> 8;
    int ef = r & 255, h = ef >> 6, e = ef & 63;
    const float* W  = sec == 0 ? Wq : sec == 1 ? Wk : Wv;
    const float* bi = sec == 0 ? bq : sec == 1 ? bk : bv;
    float scale = sec == 0 ? 0.125f : 1.0f;
    float val = ((c >> 6) == h) ? W[(((size_t)l * H + h) * 64 + e) * 64 + (c & 63)] * scale : 0.f;
    Wout[((size_t)l * 768 + r) * 256 + c] = f2b(val);
    if (c == 0) bout[(size_t)l * 768 + r] = bi[((size_t)l * H + h) * 64 + e] * scale;
}

// ---------------------------------------------------------------------------
// MFMA GEMM: Y = epi(X @ W^T + bias). X[M][K] bf16, W[F][K] bf16.
// BM=64 BN=128 BK=32, 256 threads = 4 waves (2x2), each wave 32x64.
// EPI 0: patch-embed (row remap + pos, f32)  1: GELU -> bf16
//     2: residual f32 add                    3: plain bf16 store
// ---------------------------------------------------------------------------
template <int EPI>
__global__ void gemm_bf16(const u16* __restrict__ X, const u16* __restrict__ W,
                          const float* __restrict__ bias, const float* __restrict__ pos,
                          float* __restrict__ Yf, u16* __restrict__ Yb,
                          int M, int F, int K) {
    __shared__ u16 Al[64][40];
    __shared__ u16 Bl[128][40];
    const int t = threadIdx.x;
    const int m0 = blockIdx.y * 64, f0 = blockIdx.x * 128;
    const int w = t >> 6, l = t & 63;
    const int wm = w >> 1, wn = w & 1;
    const int q = l & 15, g = l >> 4;

    f32x4 acc[2][4];
    const f32x4 zz = {0.f, 0.f, 0.f, 0.f};
#pragma unroll
    for (int i = 0; i < 2; ++i)
#pragma unroll
        for (int j = 0; j < 4; ++j) acc[i][j] = zz;

    const int lrow = t >> 2, lc8 = (t & 3) * 8;
    for (int k0 = 0; k0 < K; k0 += 32) {
        uint4 av = {0, 0, 0, 0};
        if (m0 + lrow < M) av = *(const uint4*)(X + (size_t)(m0 + lrow) * K + k0 + lc8);
        *(uint4*)&Al[lrow][lc8] = av;
#pragma unroll
        for (int it = 0; it < 2; ++it) {
            int row = lrow + 64 * it;
            *(uint4*)&Bl[row][lc8] = *(const uint4*)(W + (size_t)(f0 + row) * K + k0 + lc8);
        }
        __syncthreads();
        bf16x8 a[2], bfr[4];
#pragma unroll
        for (int fi = 0; fi < 2; ++fi) a[fi] = *(const bf16x8*)&Al[wm * 32 + fi * 16 + q][g * 8];
#pragma unroll
        for (int fj = 0; fj < 4; ++fj) bfr[fj] = *(const bf16x8*)&Bl[wn * 64 + fj * 16 + q][g * 8];
#pragma unroll
        for (int fi = 0; fi < 2; ++fi)
#pragma unroll
            for (int fj = 0; fj < 4; ++fj)
                acc[fi][fj] = __builtin_amdgcn_mfma_f32_16x16x32_bf16(a[fi], bfr[fj], acc[fi][fj], 0, 0, 0);
        __syncthreads();
    }

#pragma unroll
    for (int fi = 0; fi < 2; ++fi) {
#pragma unroll
        for (int r = 0; r < 4; ++r) {
            int m = m0 + wm * 32 + fi * 16 + g * 4 + r;
            if (m >= M) continue;
#pragma unroll
            for (int fj = 0; fj < 4; ++fj) {
                int f = f0 + wn * 64 + fj * 16 + q;
                float val = acc[fi][fj][r] + bias[f];
                if constexpr (EPI == 0) {
                    int s = m & 1023, bb = m >> 10;
                    size_t n = (size_t)bb * SP + s + 1;
                    Yf[n * D + f] = val + pos[(size_t)(s + 1) * D + f];
                } else if constexpr (EPI == 1) {
                    float gel = 0.5f * val * (1.0f + erff(val * 0.70710678118654752f));
                    Yb[(size_t)m * F + f] = f2b(gel);
                } else if constexpr (EPI == 2) {
                    Yf[(size_t)m * F + f] += val;
                } else {
                    Yb[(size_t)m * F + f] = f2b(val);
                }
            }
        }
    }
}

// ---------------------------------------------------------------------------
// LayerNorm, one wave per row, float4 loads, bf16 out. grid = N/4 blocks x 256.
// ---------------------------------------------------------------------------
__global__ void layernorm_bf16(const float* __restrict__ src,
                               const float* __restrict__ gw,
                               const float* __restrict__ bw,
                               u16* __restrict__ dst) {
    int row = blockIdx.x * 4 + (threadIdx.x >> 6);
    int l = threadIdx.x & 63;
    float4 v = *(const float4*)(src + (size_t)row * D + l * 4);
    float s = v.x + v.y + v.z + v.w;
    for (int off = 32; off; off >>= 1) s += __shfl_xor(s, off, 64);
    float mean = s * (1.0f / D);
    float dx0 = v.x - mean, dx1 = v.y - mean, dx2 = v.z - mean, dx3 = v.w - mean;
    float sq = dx0 * dx0 + dx1 * dx1 + dx2 * dx2 + dx3 * dx3;
    for (int off = 32; off; off >>= 1) sq += __shfl_xor(sq, off, 64);
    float rs = rsqrtf(sq * (1.0f / D) + 1e-5f);
    float4 gv = *(const float4*)(gw + l * 4);
    float4 bv = *(const float4*)(bw + l * 4);
    ushort4 o;
    o.x = f2b(dx0 * rs * gv.x + bv.x);
    o.y = f2b(dx1 * rs * gv.y + bv.y);
    o.z = f2b(dx2 * rs * gv.z + bv.z);
    o.w = f2b(dx3 * rs * gv.w + bv.w);
    *(ushort4*)(dst + (size_t)row * D + l * 4) = o;
}

// ---------------------------------------------------------------------------
// Flash attention, split-KV x2. grid (17 qtiles, 32 bh, 2 halves), 256 thr.
// qkv layout [N][768]: Q cols h*64, K cols 256+h*64, V cols 512+h*64.
// KVBLK=64, double-buffered swizzled LDS (chunk ^= ((row>>3)^row)&7).
// Outputs unnormalized partial O + (m,l) per row.
// ---------------------------------------------------------------------------
__global__ __launch_bounds__(256) void attn_mfma(const u16* __restrict__ qkv,
                                                 float* __restrict__ opart,
                                                 float* __restrict__ ml) {
    const int qt = blockIdx.x, bh = blockIdx.y, half = blockIdx.z;
    const int h = bh & 3, b = bh >> 2;
    const int t = threadIdx.x, w = t >> 6, l = t & 63;
    const int q = l & 15, g = l >> 4;
    const int q0 = qt * 64 + w * 16;

    __shared__ u16 Kl[2][64 * 64];
    __shared__ u16 Vt[2][64 * 64];

    const int kv_start = half * 512;
    const int kv_len = half ? (SP - 512) : 512;   // 512 or 513
    const int ntiles = (kv_len + 63) >> 6;        // 8 or 9

    int qr = q0 + q; if (qr > S) qr = S;
    const u16* qrow = qkv + ((size_t)b * SP + qr) * 768 + h * 64;
    const bf16x8 qf0 = *(const bf16x8*)(qrow + g * 8);
    const bf16x8 qf1 = *(const bf16x8*)(qrow + 32 + g * 8);

    const int sr = t >> 3;        // 0..31
    const int sc = t & 7;         // 16B chunk 0..7

    uint4 kst[2], vst[2];
    auto issue = [&](int kv0) {
#pragma unroll
        for (int i = 0; i < 2; ++i) {
            int kv = kv_start + kv0 + sr + 32 * i;
            if (kv > S) kv = S;
            const u16* base = qkv + ((size_t)b * SP + kv) * 768 + h * 64 + sc * 8;
            kst[i] = *(const uint4*)(base + 256);
            vst[i] = *(const uint4*)(base + 512);
        }
    };
    auto commit = [&](int pb) {
#pragma unroll
        for (int i = 0; i < 2; ++i) {
            int r = sr + 32 * i;
            int pk = ((r >> 3) ^ r) & 7;
            *(uint4*)&Kl[pb][r * 64 + ((sc ^ pk) & 7) * 8] = kst[i];
            const u16* pv16 = (const u16*)&vst[i];
#pragma unroll
            for (int j = 0; j < 8; ++j) {
                int d = sc * 8 + j;
                Vt[pb][d * 64 + (((r >> 3) ^ sc ^ j) & 7) * 8 + (r & 7)] = pv16[j];
            }
        }
    };

    f32x4 o[4];
    const f32x4 zz = {0.f, 0.f, 0.f, 0.f};
#pragma unroll
    for (int d = 0; d < 4; ++d) o[d] = zz;
    float m_run = -1e30f, l_run = 0.f;

    issue(0); commit(0); __syncthreads();
    int pb = 0;

    for (int tile = 0; tile < ntiles; ++tile) {
        const int kv0 = tile * 64;
        const bool pre = (tile + 1 < ntiles);
        if (pre) issue(kv0 + 64);

        // swapped QK^T: S^T[kv][qrow]
        f32x4 s[4];
#pragma unroll
        for (int kb = 0; kb < 4; ++kb) {
            s[kb] = zz;
            int r = kb * 16 + q;
            int pq = ((r >> 3) ^ r) & 7;
            bf16x8 ka0 = *(const bf16x8*)&Kl[pb][r * 64 + ((g ^ pq) & 7) * 8];
            bf16x8 ka1 = *(const bf16x8*)&Kl[pb][r * 64 + (((g + 4) ^ pq) & 7) * 8];
            s[kb] = __builtin_amdgcn_mfma_f32_16x16x32_bf16(ka0, qf0, s[kb], 0, 0, 0);
            s[kb] = __builtin_amdgcn_mfma_f32_16x16x32_bf16(ka1, qf1, s[kb], 0, 0, 0);
        }

        float sv[16];
#pragma unroll
        for (int kb = 0; kb < 4; ++kb)
#pragma unroll
            for (int r = 0; r < 4; ++r) sv[kb * 4 + r] = s[kb][r];

        if (kv0 + 64 > kv_len) {
#pragma unroll
            for (int kb = 0; kb < 4; ++kb)
#pragma unroll
                for (int r = 0; r < 4; ++r)
                    if (kv0 + kb * 16 + g * 4 + r >= kv_len) sv[kb * 4 + r] = -1e30f;
        }

        float mt = sv[0];
#pragma unroll
        for (int j = 1; j < 16; ++j) mt = fmaxf(mt, sv[j]);
        mt = fmaxf(mt, __shfl_xor(mt, 16));
        mt = fmaxf(mt, __shfl_xor(mt, 32));
        float m_new = fmaxf(m_run, mt);
        float corr = __expf(m_run - m_new);
        float ps = 0.f;
#pragma unroll
        for (int j = 0; j < 16; ++j) { sv[j] = __expf(sv[j] - m_new); ps += sv[j]; }
        ps += __shfl_xor(ps, 16);
        ps += __shfl_xor(ps, 32);
        l_run = l_run * corr + ps;
        m_run = m_new;

#pragma unroll
        for (int r = 0; r < 4; ++r) {
            float scl = __shfl(corr, g * 4 + r);
#pragma unroll
            for (int d = 0; d < 4; ++d) o[d][r] *= scl;
        }

        // P fragments (A-operand) for kv 0..31 and 32..63
        union { u32 u[4]; bf16x8 v; } pa0, pa1;
        {
            u32 t1a = pk2(sv[0], sv[1]),  t1b = pk2(sv[2], sv[3]);
            u32 t2a = pk2(sv[4], sv[5]),  t2b = pk2(sv[6], sv[7]);
            int s0i = q + 16 * ((2 * g) & 3);
            int s1i = q + 16 * ((2 * g + 1) & 3);
            u32 c0a = (u32)__shfl((int)t1a, s0i), c0b = (u32)__shfl((int)t1b, s0i);
            u32 d0a = (u32)__shfl((int)t2a, s0i), d0b = (u32)__shfl((int)t2b, s0i);
            u32 c1a = (u32)__shfl((int)t1a, s1i), c1b = (u32)__shfl((int)t1b, s1i);
            u32 d1a = (u32)__shfl((int)t2a, s1i), d1b = (u32)__shfl((int)t2b, s1i);
            pa0.u[0] = (g < 2) ? c0a : d0a;
            pa0.u[1] = (g < 2) ? c0b : d0b;
            pa0.u[2] = (g < 2) ? c1a : d1a;
            pa0.u[3] = (g < 2) ? c1b : d1b;
        }
        {
            u32 t1a = pk2(sv[8], sv[9]),   t1b = pk2(sv[10], sv[11]);
            u32 t2a = pk2(sv[12], sv[13]), t2b = pk2(sv[14], sv[15]);
            int s0i = q + 16 * ((2 * g) & 3);
            int s1i = q + 16 * ((2 * g + 1) & 3);
            u32 c0a = (u32)__shfl((int)t1a, s0i), c0b = (u32)__shfl((int)t1b, s0i);
            u32 d0a = (u32)__shfl((int)t2a, s0i), d0b = (u32)__shfl((int)t2b, s0i);
            u32 c1a = (u32)__shfl((int)t1a, s1i), c1b = (u32)__shfl((int)t1b, s1i);
            u32 d1a = (u32)__shfl((int)t2a, s1i), d1b = (u32)__shfl((int)t2b, s1i);
            pa1.u[0] = (g < 2) ? c0a : d0a;
            pa1.u[1] = (g < 2) ? c0b : d0b;
            pa1.u[2] = (g < 2) ? c1a : d1a;
            pa1.u[3] = (g < 2) ? c1b : d1b;
        }

#pragma unroll
        for (int d = 0; d < 4; ++d) {
            int rv = d * 16 + q;
            int pv = ((rv >> 3) ^ rv) & 7;
            bf16x8 vfA = *(const bf16x8*)&Vt[pb][rv * 64 + ((g ^ pv) & 7) * 8];
            bf16x8 vfB = *(const bf16x8*)&Vt[pb][rv * 64 + (((g + 4) ^ pv) & 7) * 8];
            o[d] = __builtin_amdgcn_mfma_f32_16x16x32_bf16(pa0.v, vfA, o[d], 0, 0, 0);
            o[d] = __builtin_amdgcn_mfma_f32_16x16x32_bf16(pa1.v, vfB, o[d], 0, 0, 0);
        }

        if (pre) commit(pb ^ 1);
        __syncthreads();
        pb ^= 1;
    }

    const size_t obase = ((size_t)half * 32 + bh) * SP;
#pragma unroll
    for (int r = 0; r < 4; ++r) {
        int qq = q0 + g * 4 + r;
        if (qq < SP) {
#pragma unroll
            for (int d = 0; d < 4; ++d)
                opart[(obase + qq) * 64 + d * 16 + q] = o[d][r];
        }
    }
    if (g == 0 && q0 + q < SP) {
        ml[(obase + q0 + q) * 2]     = m_run;
        ml[(obase + q0 + q) * 2 + 1] = l_run;
    }
}

// ---------------------------------------------------------------------------
// Merge the two KV-half partials, normalize, residual-add into x.
// grid (ceil(SP/4)=257, 32), block 256: 4 q-rows x 64 d.
// ---------------------------------------------------------------------------
__global__ void attn_combine(const float* __restrict__ opart, const float* __restrict__ ml,
                             float* __restrict__ x) {
    int bh = blockIdx.y;
    int qq = blockIdx.x * 4 + (threadIdx.x >> 6);
    if (qq >= SP) return;
    int d = threadIdx.x & 63;
    int h = bh & 3, b = bh >> 2;
    size_t i0 = (size_t)bh * SP + qq;
    size_t i1 = ((size_t)32 + bh) * SP + qq;
    float m1 = ml[i0 * 2], l1 = ml[i0 * 2 + 1];
    float m2 = ml[i1 * 2], l2 = ml[i1 * 2 + 1];
    float m = fmaxf(m1, m2);
    float w1 = __expf(m1 - m), w2 = __expf(m2 - m);
    float oo = (opart[i0 * 64 + d] * w1 + opart[i1 * 64 + d] * w2) / (l1 * w1 + l2 * w2);
    x[((size_t)b * SP + qq) * D + h * 64 + d] += oo;
}

// ---------------------------------------------------------------------------
__global__ void head_kernel(const float* __restrict__ x,
                            const float* __restrict__ Wo,
                            const float* __restrict__ bo,
                            float* __restrict__ out) {
    __shared__ float logits[B][O];
    int t = threadIdx.x;
    if (t < B * O) {
        int b = t / O, o = t % O;
        const float* xr = x + (size_t)b * SP * D;
        float acc = bo[o];
        for (int d = 0; d < D; ++d) acc += xr[d] * Wo[(size_t)o * D + d];
        logits[b][o] = acc;
    }
    __syncthreads();
    if (t < B) {
        float mx = -1e30f;
        for (int o = 0; o < O; ++o) mx = fmaxf(mx, logits[t][o]);
        float s = 0.f, e[O];
        for (int o = 0; o < O; ++o) { e[o] = expf(logits[t][o] - mx); s += e[o]; }
        float inv = 1.0f / s;
        for (int o = 0; o < O; ++o) out[t * O + o] = e[o] * inv;
    }
}

// ---------------------------------------------------------------------------
extern "C" void kernel_launch(void* const* d_in, const int* in_sizes, int n_in,
                              void* d_out, int out_size, void* d_ws, size_t ws_size,
                              hipStream_t stream) {
    const float* images = (const float*)d_in[0];
    const float* Wp     = (const float*)d_in[1];
    const float* bp     = (const float*)d_in[2];
    const float* cls    = (const float*)d_in[3];
    const float* pos    = (const float*)d_in[4];
    const float* ln1_g  = (const float*)d_in[5];
    const float* ln1_b  = (const float*)d_in[6];
    const float* Wq     = (const float*)d_in[7];
    const float* bq     = (const float*)d_in[8];
    const float* Wk     = (const float*)d_in[9];
    const float* bk     = (const float*)d_in[10];
    const float* Wv     = (const float*)d_in[11];
    const float* bv     = (const float*)d_in[12];
    const float* ln2_g  = (const float*)d_in[13];
    const float* ln2_b  = (const float*)d_in[14];
    const float* W1     = (const float*)d_in[15];
    const float* b1     = (const float*)d_in[16];
    const float* W2     = (const float*)d_in[17];
    const float* b2     = (const float*)d_in[18];
    const float* Wo     = (const float*)d_in[19];
    const float* bo     = (const float*)d_in[20];
    float* out = (float*)d_out;

    auto align256 = [](size_t v) { return (v + 255) & ~(size_t)255; };
    char* p = (char*)d_ws;
    float* x     = (float*)p; p += align256((size_t)N * D * 4);
    u16* lnb     = (u16*)p;   p += align256((size_t)N * D * 2);
    u16* qkvbuf  = (u16*)p;   p += align256((size_t)N * 768 * 2);
    char* midop  = p;         p += align256((size_t)N * DF * 2);   // mid (bf16) / opart (f32) alias
    float* ml    = (float*)p; p += align256((size_t)2 * 32 * SP * 2 * 4);
    u16* imgb    = (u16*)p;   p += align256((size_t)B * S * P * 2);
    u16* Wpb     = (u16*)p;   p += align256((size_t)D * P * 2);
    u16* W1b     = (u16*)p;   p += align256((size_t)L * DF * D * 2);
    u16* W2b     = (u16*)p;   p += align256((size_t)L * D * DF * 2);
    u16* Wqkvb   = (u16*)p;   p += align256((size_t)L * 768 * 256 * 2);
    float* bqkvf = (float*)p; p += align256((size_t)L * 768 * 4);
    u16* mid     = (u16*)midop;
    float* opart = (float*)midop;

    // one-time conversions / weight builds
    cvt_bf16<<<(B * S * P / 4 + 255) / 256, 256, 0, stream>>>(images, imgb, B * S * P / 4);
    cvt_bf16<<<(D * P / 4 + 255) / 256, 256, 0, stream>>>(Wp, Wpb, D * P / 4);
    cvt_bf16<<<(L * DF * D / 4 + 255) / 256, 256, 0, stream>>>(W1, W1b, L * DF * D / 4);
    cvt_bf16<<<(L * D * DF / 4 + 255) / 256, 256, 0, stream>>>(W2, W2b, L * D * DF / 4);
    build_wqkv<<<dim3(768, L), 256, 0, stream>>>(Wq, bq, Wk, bk, Wv, bv, Wqkvb, bqkvf);

    // patch embed as GEMM (M=8192, F=256, K=128) + cls rows
    gemm_bf16<0><<<dim3(D / 128, (B * S) / 64), 256, 0, stream>>>(
        imgb, Wpb, bp, pos, x, nullptr, B * S, D, P);
    cls_kernel<<<B, D, 0, stream>>>(cls, pos, x);

    for (int l = 0; l < L; ++l) {
        layernorm_bf16<<<N / 4, 256, 0, stream>>>(x, ln1_g + l * D, ln1_b + l * D, lnb);
        gemm_bf16<3><<<dim3(768 / 128, (N + 63) / 64), 256, 0, stream>>>(
            lnb, Wqkvb + (size_t)l * 768 * 256, bqkvf + (size_t)l * 768,
            nullptr, nullptr, qkvbuf, N, 768, D);
        attn_mfma<<<dim3(17, 32, 2), 256, 0, stream>>>(qkvbuf, opart, ml);
        attn_combine<<<dim3((SP + 3) / 4, 32), 256, 0, stream>>>(opart, ml, x);
        layernorm_bf16<<<N / 4, 256, 0, stream>>>(x, ln2_g + l * D, ln2_b + l * D, lnb);
        gemm_bf16<1><<<dim3(DF / 128, (N + 63) / 64), 256, 0, stream>>>(
            lnb, W1b + (size_t)l * DF * D, b1 + (size_t)l * DF, nullptr, nullptr, mid, N, DF, D);
        gemm_bf16<2><<<dim3(D / 128, (N + 63) / 64), 256, 0, stream>>>(
            mid, W2b + (size_t)l * D * DF, b2 + (size_t)l * D, nullptr, x, nullptr, N, D, DF);
    }

    head_kernel<<<1, 256, 0, stream>>>(x, Wo, bo, out);
}

// Round 4
// 467.541 us; speedup vs baseline: 14.3488x; 1.0108x over previous
//
#include <hip/hip_runtime.h>
#include <hip/hip_bf16.h>
#include <cmath>

constexpr int B  = 8;
constexpr int S  = 1024;
constexpr int P  = 128;
constexpr int D  = 256;
constexpr int H  = 4;
constexpr int L  = 4;
constexpr int DF = 1024;
constexpr int O  = 10;
constexpr int DH = D / H;       // 64
constexpr int SP = S + 1;       // 1025
constexpr int N  = B * SP;      // 8200

typedef short bf16x8 __attribute__((ext_vector_type(8)));
typedef float f32x4 __attribute__((ext_vector_type(4)));
typedef unsigned int u32;
typedef unsigned short u16;

static __device__ __forceinline__ u16 f2b(float f) {
    __hip_bfloat16 h = __float2bfloat16(f);
    u16 u; __builtin_memcpy(&u, &h, 2);
    return u;
}
static __device__ __forceinline__ float b2f(u16 u) {
    u32 uu = (u32)u << 16; float f; __builtin_memcpy(&f, &uu, 4);
    return f;
}
static __device__ __forceinline__ u32 pk2(float a, float b) {
    return (u32)f2b(a) | ((u32)f2b(b) << 16);
}
static __device__ __forceinline__ void gload_lds16(const void* g, void* l) {
    __builtin_amdgcn_global_load_lds((const __attribute__((address_space(1))) unsigned int*)g,
                                     (__attribute__((address_space(3))) unsigned int*)l, 16, 0, 0);
}

// ---------------------------------------------------------------------------
__global__ void cvt_bf16(const float* __restrict__ src, u16* __restrict__ dst, int n4) {
    int i = blockIdx.x * 256 + threadIdx.x;
    if (i < n4) {
        float4 v = ((const float4*)src)[i];
        ushort4 o;
        o.x = f2b(v.x); o.y = f2b(v.y); o.z = f2b(v.z); o.w = f2b(v.w);
        ((ushort4*)dst)[i] = o;
    }
}

// ---------------------------------------------------------------------------
__global__ void cls_kernel(const float* __restrict__ cls, const float* __restrict__ pos,
                           float* __restrict__ x) {
    int b = blockIdx.x, t = threadIdx.x;
    x[(size_t)b * SP * D + t] = cls[t] + pos[t];
}

// ---------------------------------------------------------------------------
// Fused block-diagonal QKV weight: Wout[l][768][256] bf16 (Q rows scaled 1/8).
// ---------------------------------------------------------------------------
__global__ void build_wqkv(const float* __restrict__ Wq, const float* __restrict__ bq,
                           const float* __restrict__ Wk, const float* __restrict__ bk,
                           const float* __restrict__ Wv, const float* __restrict__ bv,
                           u16* __restrict__ Wout, float* __restrict__ bout) {
    int r = blockIdx.x, l = blockIdx.y, c = threadIdx.x;
    int sec = r >> 8;
    int ef = r & 255, h = ef >> 6, e = ef & 63;
    const float* W  = sec == 0 ? Wq : sec == 1 ? Wk : Wv;
    const float* bi = sec == 0 ? bq : sec == 1 ? bk : bv;
    float scale = sec == 0 ? 0.125f : 1.0f;
    float val = ((c >> 6) == h) ? W[(((size_t)l * H + h) * 64 + e) * 64 + (c & 63)] * scale : 0.f;
    Wout[((size_t)l * 768 + r) * 256 + c] = f2b(val);
    if (c == 0) bout[(size_t)l * 768 + r] = bi[((size_t)l * H + h) * 64 + e] * scale;
}

// ---------------------------------------------------------------------------
// MFMA GEMM, 2-phase global_load_lds pipeline.
// X[M][K] bf16, W[F][K] bf16. BM=64 BN=128 BK=64, 4 waves (2x2), 1 barrier/K-step.
// LDS tiles stored with chunk-XOR swizzle: phys chunk p of row r holds logical
// chunk p ^ (r&7); the global SOURCE is pre-swizzled, reads apply the same XOR.
// EPI 0: patch-embed (row remap + pos, f32)   1: GELU -> bf16
//     3: plain bf16 store                     4: f32 partial store (split-K, no bias)
// kOff = blockIdx.z * kLen.
// ---------------------------------------------------------------------------
template <int EPI>
__global__ __launch_bounds__(256) void gemm_bf16(
        const u16* __restrict__ X, const u16* __restrict__ W,
        const float* __restrict__ bias, const float* __restrict__ pos,
        float* __restrict__ Yf, u16* __restrict__ Yb,
        int M, int F, int K, int kLen) {
    __shared__ u16 Al[2][64 * 64];
    __shared__ u16 Bl[2][128 * 64];
    const int t = threadIdx.x;
    const int m0 = blockIdx.y * 64, f0 = blockIdx.x * 128;
    const int w = t >> 6, l = t & 63;
    const int wm = w >> 1, wn = w & 1;
    const int q = l & 15, g = l >> 4;
    const int kOff = blockIdx.z * kLen;
    const int lr8 = l >> 3, lp = l & 7;

    f32x4 acc[2][4];
    const f32x4 zz = {0.f, 0.f, 0.f, 0.f};
#pragma unroll
    for (int i = 0; i < 2; ++i)
#pragma unroll
        for (int j = 0; j < 4; ++j) acc[i][j] = zz;

    auto stage = [&](int sb, int kbase) {
#pragma unroll
        for (int i = 0; i < 2; ++i) {
            int ca = w + 4 * i;                  // 0..7
            int row = ca * 8 + lr8;
            int j = lp ^ (row & 7);
            gload_lds16(X + (size_t)(m0 + row) * K + kbase + j * 8, &Al[sb][ca * 512]);
        }
#pragma unroll
        for (int i = 0; i < 4; ++i) {
            int cb = w + 4 * i;                  // 0..15
            int row = cb * 8 + lr8;
            int j = lp ^ (row & 7);
            gload_lds16(W + (size_t)(f0 + row) * K + kbase + j * 8, &Bl[sb][cb * 512]);
        }
    };

    const int nt = kLen / 64;
    stage(0, kOff);
    __syncthreads();
    int sb = 0;
    for (int ts = 0; ts < nt; ++ts) {
        if (ts + 1 < nt) stage(sb ^ 1, kOff + (ts + 1) * 64);
#pragma unroll
        for (int kk = 0; kk < 2; ++kk) {
            bf16x8 a[2], bfr[4];
#pragma unroll
            for (int fi = 0; fi < 2; ++fi) {
                int row = wm * 32 + fi * 16 + q;
                a[fi] = *(const bf16x8*)&Al[sb][row * 64 + (((kk * 4 + g) ^ (row & 7)) * 8)];
            }
#pragma unroll
            for (int fj = 0; fj < 4; ++fj) {
                int row = wn * 64 + fj * 16 + q;
                bfr[fj] = *(const bf16x8*)&Bl[sb][row * 64 + (((kk * 4 + g) ^ (row & 7)) * 8)];
            }
#pragma unroll
            for (int fi = 0; fi < 2; ++fi)
#pragma unroll
                for (int fj = 0; fj < 4; ++fj)
                    acc[fi][fj] = __builtin_amdgcn_mfma_f32_16x16x32_bf16(a[fi], bfr[fj], acc[fi][fj], 0, 0, 0);
        }
        __syncthreads();
        sb ^= 1;
    }

#pragma unroll
    for (int fi = 0; fi < 2; ++fi) {
#pragma unroll
        for (int r = 0; r < 4; ++r) {
            int m = m0 + wm * 32 + fi * 16 + g * 4 + r;
            if (m >= M) continue;
#pragma unroll
            for (int fj = 0; fj < 4; ++fj) {
                int f = f0 + wn * 64 + fj * 16 + q;
                float val = acc[fi][fj][r];
                if constexpr (EPI == 0) {
                    val += bias[f];
                    int s = m & 1023, bb = m >> 10;
                    size_t n = (size_t)bb * SP + s + 1;
                    Yf[n * D + f] = val + pos[(size_t)(s + 1) * D + f];
                } else if constexpr (EPI == 1) {
                    val += bias[f];
                    float gel = 0.5f * val * (1.0f + erff(val * 0.70710678118654752f));
                    Yb[(size_t)m * F + f] = f2b(gel);
                } else if constexpr (EPI == 3) {
                    val += bias[f];
                    Yb[(size_t)m * F + f] = f2b(val);
                } else {
                    (Yf + (size_t)blockIdx.z * M * F)[(size_t)m * F + f] = val;
                }
            }
        }
    }
}

// ---------------------------------------------------------------------------
// mlp2 split-K combine: x += P0 + P1 + bias. float4 over N*D.
// ---------------------------------------------------------------------------
__global__ void mlp2_combine(const float* __restrict__ Pk, const float* __restrict__ b2,
                             float* __restrict__ x) {
    int i = blockIdx.x * 256 + threadIdx.x;
    float4 p0 = ((const float4*)Pk)[i];
    float4 p1 = ((const float4*)(Pk + (size_t)N * D))[i];
    float4 xv = ((float4*)x)[i];
    int f = (i * 4) & (D - 1);
    xv.x += p0.x + p1.x + b2[f];
    xv.y += p0.y + p1.y + b2[f + 1];
    xv.z += p0.z + p1.z + b2[f + 2];
    xv.w += p0.w + p1.w + b2[f + 3];
    ((float4*)x)[i] = xv;
}

// ---------------------------------------------------------------------------
// LayerNorm, one wave per row, float4 loads, bf16 out.
// ---------------------------------------------------------------------------
__global__ void layernorm_bf16(const float* __restrict__ src,
                               const float* __restrict__ gw,
                               const float* __restrict__ bw,
                               u16* __restrict__ dst) {
    int row = blockIdx.x * 4 + (threadIdx.x >> 6);
    int l = threadIdx.x & 63;
    float4 v = *(const float4*)(src + (size_t)row * D + l * 4);
    float s = v.x + v.y + v.z + v.w;
    for (int off = 32; off; off >>= 1) s += __shfl_xor(s, off, 64);
    float mean = s * (1.0f / D);
    float dx0 = v.x - mean, dx1 = v.y - mean, dx2 = v.z - mean, dx3 = v.w - mean;
    float sq = dx0 * dx0 + dx1 * dx1 + dx2 * dx2 + dx3 * dx3;
    for (int off = 32; off; off >>= 1) sq += __shfl_xor(sq, off, 64);
    float rs = rsqrtf(sq * (1.0f / D) + 1e-5f);
    float4 gv = *(const float4*)(gw + l * 4);
    float4 bv = *(const float4*)(bw + l * 4);
    ushort4 o;
    o.x = f2b(dx0 * rs * gv.x + bv.x);
    o.y = f2b(dx1 * rs * gv.y + bv.y);
    o.z = f2b(dx2 * rs * gv.z + bv.z);
    o.w = f2b(dx3 * rs * gv.w + bv.w);
    *(ushort4*)(dst + (size_t)row * D + l * 4) = o;
}

// ---------------------------------------------------------------------------
// Flash attention, split-KV x4. grid (17, 32, 4), 256 thr = 4 waves x 16 q-rows.
// Single 16KB LDS buffer (2 barriers/tile), reg-prefetch issue-early/commit-late.
// Outputs NORMALIZED partial O (bf16) + (m,l) f32 per row.
// ---------------------------------------------------------------------------
__global__ __launch_bounds__(256) void attn_mfma(const u16* __restrict__ qkv,
                                                 u16* __restrict__ opart,
                                                 float* __restrict__ ml) {
    const int qt = blockIdx.x, bh = blockIdx.y, half = blockIdx.z;
    const int h = bh & 3, b = bh >> 2;
    const int t = threadIdx.x, w = t >> 6, l = t & 63;
    const int q = l & 15, g = l >> 4;
    const int q0 = qt * 64 + w * 16;

    __shared__ u16 Kl[64 * 64];
    __shared__ u16 Vt[64 * 64];

    const int kv_start = half * 256;
    const int kv_len = (half == 3) ? (SP - 768) : 256;   // 256 or 257
    const int ntiles = (kv_len + 63) >> 6;               // 4 or 5

    int qr = q0 + q; if (qr > S) qr = S;
    const u16* qrow = qkv + ((size_t)b * SP + qr) * 768 + h * 64;
    const bf16x8 qf0 = *(const bf16x8*)(qrow + g * 8);
    const bf16x8 qf1 = *(const bf16x8*)(qrow + 32 + g * 8);

    const int sr = t >> 3;        // 0..31
    const int sc = t & 7;         // 16B chunk 0..7

    uint4 kst[2], vst[2];
    auto issue = [&](int kv0) {
#pragma unroll
        for (int i = 0; i < 2; ++i) {
            int kv = kv_start + kv0 + sr + 32 * i;
            if (kv > S) kv = S;
            const u16* base = qkv + ((size_t)b * SP + kv) * 768 + h * 64 + sc * 8;
            kst[i] = *(const uint4*)(base + 256);
            vst[i] = *(const uint4*)(base + 512);
        }
    };
    auto commit = [&]() {
#pragma unroll
        for (int i = 0; i < 2; ++i) {
            int r = sr + 32 * i;
            int pk = ((r >> 3) ^ r) & 7;
            *(uint4*)&Kl[r * 64 + ((sc ^ pk) & 7) * 8] = kst[i];
            const u16* pv16 = (const u16*)&vst[i];
#pragma unroll
            for (int j = 0; j < 8; ++j) {
                int d = sc * 8 + j;
                Vt[d * 64 + (((r >> 3) ^ sc ^ j) & 7) * 8 + (r & 7)] = pv16[j];
            }
        }
    };

    f32x4 o[4];
    const f32x4 zz = {0.f, 0.f, 0.f, 0.f};
#pragma unroll
    for (int d = 0; d < 4; ++d) o[d] = zz;
    float m_run = -1e30f, l_run = 0.f;

    issue(0);
    for (int tile = 0; tile < ntiles; ++tile) {
        const int kv0 = tile * 64;
        commit();
        __syncthreads();
        if (tile + 1 < ntiles) issue(kv0 + 64);

        // swapped QK^T: S^T[kv][qrow]
        f32x4 s[4];
        __builtin_amdgcn_s_setprio(1);
#pragma unroll
        for (int kb = 0; kb < 4; ++kb) {
            s[kb] = zz;
            int r = kb * 16 + q;
            int pq = ((r >> 3) ^ r) & 7;
            bf16x8 ka0 = *(const bf16x8*)&Kl[r * 64 + ((g ^ pq) & 7) * 8];
            bf16x8 ka1 = *(const bf16x8*)&Kl[r * 64 + (((g + 4) ^ pq) & 7) * 8];
            s[kb] = __builtin_amdgcn_mfma_f32_16x16x32_bf16(ka0, qf0, s[kb], 0, 0, 0);
            s[kb] = __builtin_amdgcn_mfma_f32_16x16x32_bf16(ka1, qf1, s[kb], 0, 0, 0);
        }
        __builtin_amdgcn_s_setprio(0);

        float sv[16];
#pragma unroll
        for (int kb = 0; kb < 4; ++kb)
#pragma unroll
            for (int r = 0; r < 4; ++r) sv[kb * 4 + r] = s[kb][r];

        if (kv0 + 64 > kv_len) {
#pragma unroll
            for (int kb = 0; kb < 4; ++kb)
#pragma unroll
                for (int r = 0; r < 4; ++r)
                    if (kv0 + kb * 16 + g * 4 + r >= kv_len) sv[kb * 4 + r] = -1e30f;
        }

        float mt = sv[0];
#pragma unroll
        for (int j = 1; j < 16; ++j) mt = fmaxf(mt, sv[j]);
        mt = fmaxf(mt, __shfl_xor(mt, 16));
        mt = fmaxf(mt, __shfl_xor(mt, 32));
        float m_new = fmaxf(m_run, mt);
        float corr = __expf(m_run - m_new);
        float ps = 0.f;
#pragma unroll
        for (int j = 0; j < 16; ++j) { sv[j] = __expf(sv[j] - m_new); ps += sv[j]; }
        ps += __shfl_xor(ps, 16);
        ps += __shfl_xor(ps, 32);
        l_run = l_run * corr + ps;
        m_run = m_new;

#pragma unroll
        for (int r = 0; r < 4; ++r) {
            float scl = __shfl(corr, g * 4 + r);
#pragma unroll
            for (int d = 0; d < 4; ++d) o[d][r] *= scl;
        }

        // P fragments (A-operand) for kv 0..31 and 32..63
        union { u32 u[4]; bf16x8 v; } pa0, pa1;
        {
            u32 t1a = pk2(sv[0], sv[1]),  t1b = pk2(sv[2], sv[3]);
            u32 t2a = pk2(sv[4], sv[5]),  t2b = pk2(sv[6], sv[7]);
            int s0i = q + 16 * ((2 * g) & 3);
            int s1i = q + 16 * ((2 * g + 1) & 3);
            u32 c0a = (u32)__shfl((int)t1a, s0i), c0b = (u32)__shfl((int)t1b, s0i);
            u32 d0a = (u32)__shfl((int)t2a, s0i), d0b = (u32)__shfl((int)t2b, s0i);
            u32 c1a = (u32)__shfl((int)t1a, s1i), c1b = (u32)__shfl((int)t1b, s1i);
            u32 d1a = (u32)__shfl((int)t2a, s1i), d1b = (u32)__shfl((int)t2b, s1i);
            pa0.u[0] = (g < 2) ? c0a : d0a;
            pa0.u[1] = (g < 2) ? c0b : d0b;
            pa0.u[2] = (g < 2) ? c1a : d1a;
            pa0.u[3] = (g < 2) ? c1b : d1b;
        }
        {
            u32 t1a = pk2(sv[8], sv[9]),   t1b = pk2(sv[10], sv[11]);
            u32 t2a = pk2(sv[12], sv[13]), t2b = pk2(sv[14], sv[15]);
            int s0i = q + 16 * ((2 * g) & 3);
            int s1i = q + 16 * ((2 * g + 1) & 3);
            u32 c0a = (u32)__shfl((int)t1a, s0i), c0b = (u32)__shfl((int)t1b, s0i);
            u32 d0a = (u32)__shfl((int)t2a, s0i), d0b = (u32)__shfl((int)t2b, s0i);
            u32 c1a = (u32)__shfl((int)t1a, s1i), c1b = (u32)__shfl((int)t1b, s1i);
            u32 d1a = (u32)__shfl((int)t2a, s1i), d1b = (u32)__shfl((int)t2b, s1i);
            pa1.u[0] = (g < 2) ? c0a : d0a;
            pa1.u[1] = (g < 2) ? c0b : d0b;
            pa1.u[2] = (g < 2) ? c1a : d1a;
            pa1.u[3] = (g < 2) ? c1b : d1b;
        }

        __builtin_amdgcn_s_setprio(1);
#pragma unroll
        for (int d = 0; d < 4; ++d) {
            int rv = d * 16 + q;
            int pv = ((rv >> 3) ^ rv) & 7;
            bf16x8 vfA = *(const bf16x8*)&Vt[rv * 64 + ((g ^ pv) & 7) * 8];
            bf16x8 vfB = *(const bf16x8*)&Vt[rv * 64 + (((g + 4) ^ pv) & 7) * 8];
            o[d] = __builtin_amdgcn_mfma_f32_16x16x32_bf16(pa0.v, vfA, o[d], 0, 0, 0);
            o[d] = __builtin_amdgcn_mfma_f32_16x16x32_bf16(pa1.v, vfB, o[d], 0, 0, 0);
        }
        __builtin_amdgcn_s_setprio(0);
        __syncthreads();
    }

    float inv = 1.0f / l_run;
    const size_t obase = ((size_t)half * 32 + bh) * SP;
#pragma unroll
    for (int r = 0; r < 4; ++r) {
        float scl = __shfl(inv, g * 4 + r);
        int qq = q0 + g * 4 + r;
        if (qq < SP) {
#pragma unroll
            for (int d = 0; d < 4; ++d)
                opart[(obase + qq) * 64 + d * 16 + q] = f2b(o[d][r] * scl);
        }
    }
    if (g == 0 && q0 + q < SP) {
        ml[(obase + q0 + q) * 2]     = m_run;
        ml[(obase + q0 + q) * 2 + 1] = l_run;
    }
}

// ---------------------------------------------------------------------------
// Merge 4 KV-quarter partials, residual-add into x. grid (257, 32), 256 thr.
// ---------------------------------------------------------------------------
__global__ void attn_combine(const u16* __restrict__ opart, const float* __restrict__ ml,
                             float* __restrict__ x) {
    int bh = blockIdx.y;
    int qq = blockIdx.x * 4 + (threadIdx.x >> 6);
    if (qq >= SP) return;
    int d = threadIdx.x & 63;
    int h = bh & 3, b = bh >> 2;
    float mi[4], li[4];
    float m = -1e30f;
#pragma unroll
    for (int i = 0; i < 4; ++i) {
        size_t idx = ((size_t)i * 32 + bh) * SP + qq;
        mi[i] = ml[idx * 2]; li[i] = ml[idx * 2 + 1];
        m = fmaxf(m, mi[i]);
    }
    float csum = 0.f, acc = 0.f;
#pragma unroll
    for (int i = 0; i < 4; ++i) {
        float c = __expf(mi[i] - m) * li[i];
        csum += c;
        acc += c * b2f(opart[(((size_t)i * 32 + bh) * SP + qq) * 64 + d]);
    }
    x[((size_t)b * SP + qq) * D + h * 64 + d] += acc / csum;
}

// ---------------------------------------------------------------------------
__global__ void head_kernel(const float* __restrict__ x,
                            const float* __restrict__ Wo,
                            const float* __restrict__ bo,
                            float* __restrict__ out) {
    __shared__ float logits[B][O];
    int t = threadIdx.x;
    if (t < B * O) {
        int b = t / O, o = t % O;
        const float* xr = x + (size_t)b * SP * D;
        float acc = bo[o];
        for (int d = 0; d < D; ++d) acc += xr[d] * Wo[(size_t)o * D + d];
        logits[b][o] = acc;
    }
    __syncthreads();
    if (t < B) {
        float mx = -1e30f;
        for (int o = 0; o < O; ++o) mx = fmaxf(mx, logits[t][o]);
        float s = 0.f, e[O];
        for (int o = 0; o < O; ++o) { e[o] = expf(logits[t][o] - mx); s += e[o]; }
        float inv = 1.0f / s;
        for (int o = 0; o < O; ++o) out[t * O + o] = e[o] * inv;
    }
}

// ---------------------------------------------------------------------------
extern "C" void kernel_launch(void* const* d_in, const int* in_sizes, int n_in,
                              void* d_out, int out_size, void* d_ws, size_t ws_size,
                              hipStream_t stream) {
    const float* images = (const float*)d_in[0];
    const float* Wp     = (const float*)d_in[1];
    const float* bp     = (const float*)d_in[2];
    const float* cls    = (const float*)d_in[3];
    const float* pos    = (const float*)d_in[4];
    const float* ln1_g  = (const float*)d_in[5];
    const float* ln1_b  = (const float*)d_in[6];
    const float* Wq     = (const float*)d_in[7];
    const float* bq     = (const float*)d_in[8];
    const float* Wk     = (const float*)d_in[9];
    const float* bk     = (const float*)d_in[10];
    const float* Wv     = (const float*)d_in[11];
    const float* bv     = (const float*)d_in[12];
    const float* ln2_g  = (const float*)d_in[13];
    const float* ln2_b  = (const float*)d_in[14];
    const float* W1     = (const float*)d_in[15];
    const float* b1     = (const float*)d_in[16];
    const float* W2     = (const float*)d_in[17];
    const float* b2     = (const float*)d_in[18];
    const float* Wo     = (const float*)d_in[19];
    const float* bo     = (const float*)d_in[20];
    float* out = (float*)d_out;

    auto align256 = [](size_t v) { return (v + 255) & ~(size_t)255; };
    char* p = (char*)d_ws;
    float* x     = (float*)p; p += align256((size_t)N * D * 4);
    u16* lnb     = (u16*)p;   p += align256((size_t)N * D * 2);    // Pk aliases lnb+qkvbuf
    u16* qkvbuf  = (u16*)p;   p += align256((size_t)N * 768 * 2);
    char* midop  = p;         p += align256((size_t)N * DF * 2);   // mid bf16 / opart bf16 alias
    float* ml    = (float*)p; p += align256((size_t)4 * 32 * SP * 2 * 4);
    u16* imgb    = (u16*)p;   p += align256((size_t)B * S * P * 2);
    u16* Wpb     = (u16*)p;   p += align256((size_t)D * P * 2);
    u16* W1b     = (u16*)p;   p += align256((size_t)L * DF * D * 2);
    u16* W2b     = (u16*)p;   p += align256((size_t)L * D * DF * 2);
    u16* Wqkvb   = (u16*)p;   p += align256((size_t)L * 768 * 256 * 2);
    float* bqkvf = (float*)p; p += align256((size_t)L * 768 * 4);
    u16* mid     = (u16*)midop;
    u16* opart   = (u16*)midop;
    float* Pk    = (float*)lnb;    // 2 x N*D f32 partials over lnb+qkvbuf (16.8MB)

    // one-time conversions / weight builds
    cvt_bf16<<<(B * S * P / 4 + 255) / 256, 256, 0, stream>>>(images, imgb, B * S * P / 4);
    cvt_bf16<<<(D * P / 4 + 255) / 256, 256, 0, stream>>>(Wp, Wpb, D * P / 4);
    cvt_bf16<<<(L * DF * D / 4 + 255) / 256, 256, 0, stream>>>(W1, W1b, L * DF * D / 4);
    cvt_bf16<<<(L * D * DF / 4 + 255) / 256, 256, 0, stream>>>(W2, W2b, L * D * DF / 4);
    build_wqkv<<<dim3(768, L), 256, 0, stream>>>(Wq, bq, Wk, bk, Wv, bv, Wqkvb, bqkvf);

    // patch embed as GEMM (M=8192, F=256, K=128) + cls rows
    gemm_bf16<0><<<dim3(2, 128, 1), 256, 0, stream>>>(
        imgb, Wpb, bp, pos, x, nullptr, B * S, D, P, P);
    cls_kernel<<<B, D, 0, stream>>>(cls, pos, x);

    for (int l = 0; l < L; ++l) {
        layernorm_bf16<<<N / 4, 256, 0, stream>>>(x, ln1_g + l * D, ln1_b + l * D, lnb);
        gemm_bf16<3><<<dim3(6, 129, 1), 256, 0, stream>>>(
            lnb, Wqkvb + (size_t)l * 768 * 256, bqkvf + (size_t)l * 768,
            nullptr, nullptr, qkvbuf, N, 768, D, D);
        attn_mfma<<<dim3(17, 32, 4), 256, 0, stream>>>(qkvbuf, opart, ml);
        attn_combine<<<dim3((SP + 3) / 4, 32), 256, 0, stream>>>(opart, ml, x);
        layernorm_bf16<<<N / 4, 256, 0, stream>>>(x, ln2_g + l * D, ln2_b + l * D, lnb);
        gemm_bf16<1><<<dim3(8, 129, 1), 256, 0, stream>>>(
            lnb, W1b + (size_t)l * DF * D, b1 + (size_t)l * DF,
            nullptr, nullptr, mid, N, DF, D, D);
        gemm_bf16<4><<<dim3(2, 129, 2), 256, 0, stream>>>(
            mid, W2b + (size_t)l * D * DF, nullptr, nullptr, Pk, nullptr, N, D, DF, DF / 2);
        mlp2_combine<<<N * D / 1024, 256, 0, stream>>>(Pk, b2 + (size_t)l * D, x);
    }

    head_kernel<<<1, 256, 0, stream>>>(x, Wo, bo, out);
}